// Round 1
// baseline (1825.123 us; speedup 1.0000x reference)
//
#include <hip/hip_runtime.h>
#include <cstdint>

#define BSZ 512
#define NG 5
#define NEL 32
#define IN_C 5
#define HC 64
#define NN (BSZ * NG * NEL)   // 81920 nodes
#define NE (NN * 16)          // 1310720 edges
#define NC 3
#define KTOT (NG * NEL * HC)  // 10240

__device__ __forceinline__ float bcast(float v, int l) {
  return __int_as_float(__builtin_amdgcn_readlane(__float_as_int(v), l));
}

__device__ __forceinline__ float sigmoidf_(float x) {
  return 1.0f / (1.0f + __expf(-x));
}

__device__ __forceinline__ float tanhf_(float x) {
  x = fminf(fmaxf(x, -15.0f), 15.0f);
  float e = __expf(2.0f * x);
  return (e - 1.0f) / (e + 1.0f);
}

// h[n][c] = c < 5 ? x[n][c] : 0
__global__ void k_init(const float* __restrict__ x, float* __restrict__ h) {
  int idx = blockIdx.x * 256 + threadIdx.x;
  int n = idx >> 6, c = idx & 63;
  h[idx] = (c < IN_C) ? x[n * IN_C + c] : 0.0f;
}

// m = h @ Wg   ([N,64] @ [64,64]); wave-per-node, Wg column in regs
__global__ void k_gemm64(const float* __restrict__ h, const float* __restrict__ Wg,
                         float* __restrict__ m) {
  const int lane = threadIdx.x & 63;
  const int gw = (blockIdx.x * blockDim.x + threadIdx.x) >> 6;
  const int nw = (gridDim.x * blockDim.x) >> 6;
  float wcol[64];
#pragma unroll
  for (int k = 0; k < 64; ++k) wcol[k] = Wg[k * 64 + lane];
  for (int n = gw; n < NN; n += nw) {
    float hv = h[n * 64 + lane];
    float acc = 0.0f;
#pragma unroll
    for (int k = 0; k < 64; ++k) acc = fmaf(bcast(hv, k), wcol[k], acc);
    m[n * 64 + lane] = acc;
  }
}

// per edge e: aggr[dst] += m[src] * ea[e]; wave-per-edge
__global__ void k_edge(const int* __restrict__ ei, const float* __restrict__ ea,
                       const float* __restrict__ m, float* __restrict__ aggr) {
  const int lane = threadIdx.x & 63;
  const int e = blockIdx.x * 4 + (threadIdx.x >> 6);
  const int src = ei[e];
  const int dst = ei[NE + e];
  const float w = ea[e];
  const float v = m[src * 64 + lane] * w;
  unsafeAtomicAdd(&aggr[dst * 64 + lane], v);
}

// GRU cell per node (thread-per-node, rows in VGPRs, uniform weight streams)
__global__ void __launch_bounds__(256) k_gru(
    const float* __restrict__ aggr, float* __restrict__ h,
    const float* __restrict__ wih, const float* __restrict__ whh,
    const float* __restrict__ bih, const float* __restrict__ bhh) {
  const int n = blockIdx.x * 256 + threadIdx.x;
  const float4* a4 = (const float4*)(aggr + (size_t)n * 64);
  const float4* h4 = (const float4*)(h + (size_t)n * 64);
  float a[64], hv[64];
#pragma unroll
  for (int i = 0; i < 16; ++i) {
    float4 t = a4[i];
    a[4 * i] = t.x; a[4 * i + 1] = t.y; a[4 * i + 2] = t.z; a[4 * i + 3] = t.w;
    float4 u = h4[i];
    hv[4 * i] = u.x; hv[4 * i + 1] = u.y; hv[4 * i + 2] = u.z; hv[4 * i + 3] = u.w;
  }
  for (int j = 0; j < 64; ++j) {
    float ir = bih[j], iz = bih[64 + j], in_ = bih[128 + j];
    float hr = bhh[j], hz = bhh[64 + j], hn = bhh[128 + j];
    const float* wr = wih + j * 64;
    const float* wz = wih + (64 + j) * 64;
    const float* wn = wih + (128 + j) * 64;
    const float* vr = whh + j * 64;
    const float* vz = whh + (64 + j) * 64;
    const float* vn = whh + (128 + j) * 64;
#pragma unroll
    for (int k = 0; k < 64; ++k) {
      ir = fmaf(a[k], wr[k], ir);
      iz = fmaf(a[k], wz[k], iz);
      in_ = fmaf(a[k], wn[k], in_);
      hr = fmaf(hv[k], vr[k], hr);
      hz = fmaf(hv[k], vz[k], hz);
      hn = fmaf(hv[k], vn[k], hn);
    }
    float r = sigmoidf_(ir + hr);
    float z = sigmoidf_(iz + hz);
    float nn2 = tanhf_(in_ + r * hn);
    float hj = h[(size_t)n * 64 + j];  // == hv[j], reload to avoid dyn reg index
    h[(size_t)n * 64 + j] = (1.0f - z) * nn2 + z * hj;
  }
}

// z1pre[bs][c] += sum over a K slice of rearranged(h) @ W1.T
// grid: 256 blocks = 64 bs-groups (8 rows) x 4 K-slices (2560 each)
__global__ void k_mlp1(const float* __restrict__ h, const float* __restrict__ W1,
                       float* __restrict__ z1) {
  __shared__ float Alds[8 * 512];
  const int tid = threadIdx.x;
  const int grp = blockIdx.x >> 2;   // 0..63
  const int sl = blockIdx.x & 3;     // K slice
  const int bs0 = grp * 8;
  const int c = tid & 63;
  const int w = tid >> 6;            // 0..3
  float acc0 = 0.0f, acc1 = 0.0f;
  for (int ch = 0; ch < 5; ++ch) {
    __syncthreads();
    const int kbase = sl * 2560 + ch * 512;
    for (int idx = tid; idx < 8 * 512; idx += 256) {
      int j = idx >> 9, kk = idx & 511;
      int kg = kbase + kk;
      int e = kg / 320;
      int r = kg - e * 320;
      int g = r >> 6, f = r & 63;
      int n = (bs0 + j) * (NG * NEL) + g * NEL + e;
      Alds[idx] = h[(size_t)n * 64 + f];
    }
    __syncthreads();
    const float* w1p = W1 + (size_t)c * KTOT + kbase;
#pragma unroll 8
    for (int kk = 0; kk < 512; ++kk) {
      float wv = w1p[kk];
      acc0 = fmaf(Alds[w * 512 + kk], wv, acc0);
      acc1 = fmaf(Alds[(w + 4) * 512 + kk], wv, acc1);
    }
  }
  unsafeAtomicAdd(&z1[(bs0 + w) * 64 + c], acc0);
  unsafeAtomicAdd(&z1[(bs0 + w + 4) * 64 + c], acc1);
}

// relu(z1+b1) -> 32 -> 16 -> 3 -> softmax; wave-per-batch-row
__global__ void k_tail(const float* __restrict__ z1, const float* __restrict__ b1,
                       const float* __restrict__ W2, const float* __restrict__ b2,
                       const float* __restrict__ W3, const float* __restrict__ b3,
                       const float* __restrict__ W4, const float* __restrict__ b4,
                       float* __restrict__ out) {
  const int lane = threadIdx.x & 63;
  const int bs = blockIdx.x * 4 + (threadIdx.x >> 6);
  float zv = fmaxf(z1[(size_t)bs * 64 + lane] + b1[lane], 0.0f);
  // 64 -> 32
  const int c2 = lane & 31;
  float acc2 = b2[c2];
#pragma unroll
  for (int k = 0; k < 64; ++k) acc2 = fmaf(bcast(zv, k), W2[c2 * 64 + k], acc2);
  acc2 = fmaxf(acc2, 0.0f);
  // 32 -> 16
  const int c3 = lane & 15;
  float acc3 = b3[c3];
#pragma unroll
  for (int k = 0; k < 32; ++k) acc3 = fmaf(bcast(acc2, k), W3[c3 * 32 + k], acc3);
  acc3 = fmaxf(acc3, 0.0f);
  // 16 -> 3 (all lanes redundantly) + softmax
  float l0 = b4[0], l1 = b4[1], l2 = b4[2];
#pragma unroll
  for (int k = 0; k < 16; ++k) {
    float v = bcast(acc3, k);
    l0 = fmaf(v, W4[k], l0);
    l1 = fmaf(v, W4[16 + k], l1);
    l2 = fmaf(v, W4[32 + k], l2);
  }
  float mx = fmaxf(l0, fmaxf(l1, l2));
  float e0 = __expf(l0 - mx), e1 = __expf(l1 - mx), e2 = __expf(l2 - mx);
  float inv = 1.0f / (e0 + e1 + e2);
  if (lane == 0) {
    out[bs * 3 + 0] = e0 * inv;
    out[bs * 3 + 1] = e1 * inv;
    out[bs * 3 + 2] = e2 * inv;
  }
}

extern "C" void kernel_launch(void* const* d_in, const int* in_sizes, int n_in,
                              void* d_out, int out_size, void* d_ws, size_t ws_size,
                              hipStream_t stream) {
  const float* x = (const float*)d_in[0];
  const int* ei = (const int*)d_in[1];
  const float* ea = (const float*)d_in[2];
  const float* Wg = (const float*)d_in[3];
  const float* wih = (const float*)d_in[4];
  const float* whh = (const float*)d_in[5];
  const float* bih = (const float*)d_in[6];
  const float* bhh = (const float*)d_in[7];
  const float* W1 = (const float*)d_in[8];
  const float* b1 = (const float*)d_in[9];
  const float* W2 = (const float*)d_in[10];
  const float* b2 = (const float*)d_in[11];
  const float* W3 = (const float*)d_in[12];
  const float* b3 = (const float*)d_in[13];
  const float* W4 = (const float*)d_in[14];
  const float* b4 = (const float*)d_in[15];
  float* out = (float*)d_out;

  float* h = (float*)d_ws;
  float* m = h + (size_t)NN * 64;
  float* aggr = m + (size_t)NN * 64;
  float* z1 = aggr + (size_t)NN * 64;

  hipMemsetAsync(z1, 0, BSZ * 64 * sizeof(float), stream);
  k_init<<<NN * 64 / 256, 256, 0, stream>>>(x, h);
  for (int layer = 0; layer < 2; ++layer) {
    hipMemsetAsync(aggr, 0, (size_t)NN * 64 * sizeof(float), stream);
    k_gemm64<<<1024, 256, 0, stream>>>(h, Wg + layer * 64 * 64, m);
    k_edge<<<NE / 4, 256, 0, stream>>>(ei, ea, m, aggr);
    k_gru<<<NN / 256, 256, 0, stream>>>(aggr, h, wih, whh, bih, bhh);
  }
  k_mlp1<<<256, 256, 0, stream>>>(h, W1, z1);
  k_tail<<<BSZ / 4, 256, 0, stream>>>(z1, b1, W2, b2, W3, b3, W4, b4, out);
}

// Round 2
// 1174.580 us; speedup vs baseline: 1.5539x; 1.5539x over previous
//
#include <hip/hip_runtime.h>
#include <cstdint>

#define BSZ 512
#define NG 5
#define NEL 32
#define IN_C 5
#define HC 64
#define NN (BSZ * NG * NEL)   // 81920 nodes
#define NE (NN * 16)          // 1310720 edges
#define NC 3
#define KTOT (NG * NEL * HC)  // 10240

__device__ __forceinline__ float bcast(float v, int l) {
  return __int_as_float(__builtin_amdgcn_readlane(__float_as_int(v), l));
}

__device__ __forceinline__ float sigmoidf_(float x) {
  return 1.0f / (1.0f + __expf(-x));
}

__device__ __forceinline__ float tanhf_(float x) {
  x = fminf(fmaxf(x, -15.0f), 15.0f);
  float e = __expf(2.0f * x);
  return (e - 1.0f) / (e + 1.0f);
}

// h[n][c] = c < 5 ? x[n][c] : 0
__global__ void k_init(const float* __restrict__ x, float* __restrict__ h) {
  int idx = blockIdx.x * 256 + threadIdx.x;
  int n = idx >> 6, c = idx & 63;
  h[idx] = (c < IN_C) ? x[n * IN_C + c] : 0.0f;
}

// m = h @ Wg   ([N,64] @ [64,64]); wave-per-node, Wg column in regs
__global__ void k_gemm64(const float* __restrict__ h, const float* __restrict__ Wg,
                         float* __restrict__ m) {
  const int lane = threadIdx.x & 63;
  const int gw = (blockIdx.x * blockDim.x + threadIdx.x) >> 6;
  const int nw = (gridDim.x * blockDim.x) >> 6;
  float wcol[64];
#pragma unroll
  for (int k = 0; k < 64; ++k) wcol[k] = Wg[k * 64 + lane];
  for (int n = gw; n < NN; n += nw) {
    float hv = h[n * 64 + lane];
    float acc = 0.0f;
#pragma unroll
    for (int k = 0; k < 64; ++k) acc = fmaf(bcast(hv, k), wcol[k], acc);
    m[n * 64 + lane] = acc;
  }
}

// per edge e: aggr[dst] += m[src] * ea[e]; wave-per-edge, grid-stride
__global__ void k_edge(const int* __restrict__ ei, const float* __restrict__ ea,
                       const float* __restrict__ m, float* __restrict__ aggr) {
  const int lane = threadIdx.x & 63;
  int w = (blockIdx.x * 256 + threadIdx.x) >> 6;
  const int nw = (gridDim.x * 256) >> 6;
  for (int e = w; e < NE; e += nw) {
    const int src = ei[e];
    const int dst = ei[NE + e];
    const float wgt = ea[e];
    const float v = m[src * 64 + lane] * wgt;
    unsafeAtomicAdd(&aggr[dst * 64 + lane], v);
  }
}

// r gate: wave-per-node, lane=output channel, weights (wr,vr) in VGPRs
__global__ void __launch_bounds__(64) k_gru_r(
    const float* __restrict__ aggr, const float* __restrict__ h,
    const float* __restrict__ wih, const float* __restrict__ whh,
    const float* __restrict__ bih, const float* __restrict__ bhh,
    float* __restrict__ rbuf) {
  const int lane = threadIdx.x;
  float wr[64], vr[64];
#pragma unroll
  for (int k = 0; k < 64; ++k) {
    wr[k] = wih[lane * 64 + k];
    vr[k] = whh[lane * 64 + k];
  }
  const float br = bih[lane] + bhh[lane];
  for (int n = blockIdx.x; n < NN; n += gridDim.x) {
    const int idx = n * 64 + lane;
    float a = aggr[idx];
    float hv = h[idx];
    float acc = br;
#pragma unroll
    for (int k = 0; k < 64; ++k) {
      acc = fmaf(bcast(a, k), wr[k], acc);
      acc = fmaf(bcast(hv, k), vr[k], acc);
    }
    rbuf[idx] = sigmoidf_(acc);
  }
}

// z + n gates + h update: weights (wz,vz,wn,vn) in VGPRs (256), 1 wave/SIMD
__global__ void __launch_bounds__(64, 1) k_gru_zn(
    const float* __restrict__ aggr, float* __restrict__ h,
    const float* __restrict__ rbuf,
    const float* __restrict__ wih, const float* __restrict__ whh,
    const float* __restrict__ bih, const float* __restrict__ bhh) {
  const int lane = threadIdx.x;
  float wz[64], vz[64], wn[64], vn[64];
#pragma unroll
  for (int k = 0; k < 64; ++k) {
    wz[k] = wih[(64 + lane) * 64 + k];
    vz[k] = whh[(64 + lane) * 64 + k];
    wn[k] = wih[(128 + lane) * 64 + k];
    vn[k] = whh[(128 + lane) * 64 + k];
  }
  const float bz = bih[64 + lane] + bhh[64 + lane];
  const float bni = bih[128 + lane];
  const float bnh = bhh[128 + lane];
  for (int n = blockIdx.x; n < NN; n += gridDim.x) {
    const int idx = n * 64 + lane;
    float a = aggr[idx];
    float hv = h[idx];
    float r = rbuf[idx];
    float az = bz, ani = bni, anh = bnh;
#pragma unroll
    for (int k = 0; k < 64; ++k) {
      float av = bcast(a, k);
      float hb = bcast(hv, k);
      az = fmaf(av, wz[k], az);
      ani = fmaf(av, wn[k], ani);
      az = fmaf(hb, vz[k], az);
      anh = fmaf(hb, vn[k], anh);
    }
    float z = sigmoidf_(az);
    float nn2 = tanhf_(ani + r * anh);
    h[idx] = (1.0f - z) * nn2 + z * hv;
  }
}

// z1pre[bs][c] += sum over a K slice of rearranged(h) @ W1.T
// grid: 256 blocks = 64 bs-groups (8 rows) x 4 K-slices (2560 each)
__global__ void k_mlp1(const float* __restrict__ h, const float* __restrict__ W1,
                       float* __restrict__ z1) {
  __shared__ float Alds[8 * 512];
  const int tid = threadIdx.x;
  const int grp = blockIdx.x >> 2;   // 0..63
  const int sl = blockIdx.x & 3;     // K slice
  const int bs0 = grp * 8;
  const int c = tid & 63;
  const int w = tid >> 6;            // 0..3
  float acc0 = 0.0f, acc1 = 0.0f;
  for (int ch = 0; ch < 5; ++ch) {
    __syncthreads();
    const int kbase = sl * 2560 + ch * 512;
    for (int idx = tid; idx < 8 * 512; idx += 256) {
      int j = idx >> 9, kk = idx & 511;
      int kg = kbase + kk;
      int e = kg / 320;
      int r = kg - e * 320;
      int g = r >> 6, f = r & 63;
      int n = (bs0 + j) * (NG * NEL) + g * NEL + e;
      Alds[idx] = h[(size_t)n * 64 + f];
    }
    __syncthreads();
    const float* w1p = W1 + (size_t)c * KTOT + kbase;
#pragma unroll 8
    for (int kk = 0; kk < 512; ++kk) {
      float wv = w1p[kk];
      acc0 = fmaf(Alds[w * 512 + kk], wv, acc0);
      acc1 = fmaf(Alds[(w + 4) * 512 + kk], wv, acc1);
    }
  }
  unsafeAtomicAdd(&z1[(bs0 + w) * 64 + c], acc0);
  unsafeAtomicAdd(&z1[(bs0 + w + 4) * 64 + c], acc1);
}

// relu(z1+b1) -> 32 -> 16 -> 3 -> softmax; wave-per-batch-row
__global__ void k_tail(const float* __restrict__ z1, const float* __restrict__ b1,
                       const float* __restrict__ W2, const float* __restrict__ b2,
                       const float* __restrict__ W3, const float* __restrict__ b3,
                       const float* __restrict__ W4, const float* __restrict__ b4,
                       float* __restrict__ out) {
  const int lane = threadIdx.x & 63;
  const int bs = blockIdx.x * 4 + (threadIdx.x >> 6);
  float zv = fmaxf(z1[(size_t)bs * 64 + lane] + b1[lane], 0.0f);
  // 64 -> 32
  const int c2 = lane & 31;
  float acc2 = b2[c2];
#pragma unroll
  for (int k = 0; k < 64; ++k) acc2 = fmaf(bcast(zv, k), W2[c2 * 64 + k], acc2);
  acc2 = fmaxf(acc2, 0.0f);
  // 32 -> 16
  const int c3 = lane & 15;
  float acc3 = b3[c3];
#pragma unroll
  for (int k = 0; k < 32; ++k) acc3 = fmaf(bcast(acc2, k), W3[c3 * 32 + k], acc3);
  acc3 = fmaxf(acc3, 0.0f);
  // 16 -> 3 (all lanes redundantly) + softmax
  float l0 = b4[0], l1 = b4[1], l2 = b4[2];
#pragma unroll
  for (int k = 0; k < 16; ++k) {
    float v = bcast(acc3, k);
    l0 = fmaf(v, W4[k], l0);
    l1 = fmaf(v, W4[16 + k], l1);
    l2 = fmaf(v, W4[32 + k], l2);
  }
  float mx = fmaxf(l0, fmaxf(l1, l2));
  float e0 = __expf(l0 - mx), e1 = __expf(l1 - mx), e2 = __expf(l2 - mx);
  float inv = 1.0f / (e0 + e1 + e2);
  if (lane == 0) {
    out[bs * 3 + 0] = e0 * inv;
    out[bs * 3 + 1] = e1 * inv;
    out[bs * 3 + 2] = e2 * inv;
  }
}

extern "C" void kernel_launch(void* const* d_in, const int* in_sizes, int n_in,
                              void* d_out, int out_size, void* d_ws, size_t ws_size,
                              hipStream_t stream) {
  const float* x = (const float*)d_in[0];
  const int* ei = (const int*)d_in[1];
  const float* ea = (const float*)d_in[2];
  const float* Wg = (const float*)d_in[3];
  const float* wih = (const float*)d_in[4];
  const float* whh = (const float*)d_in[5];
  const float* bih = (const float*)d_in[6];
  const float* bhh = (const float*)d_in[7];
  const float* W1 = (const float*)d_in[8];
  const float* b1 = (const float*)d_in[9];
  const float* W2 = (const float*)d_in[10];
  const float* b2 = (const float*)d_in[11];
  const float* W3 = (const float*)d_in[12];
  const float* b3 = (const float*)d_in[13];
  const float* W4 = (const float*)d_in[14];
  const float* b4 = (const float*)d_in[15];
  float* out = (float*)d_out;

  float* h = (float*)d_ws;
  float* m = h + (size_t)NN * 64;      // also reused as rbuf (dead after k_edge)
  float* aggr = m + (size_t)NN * 64;
  float* z1 = aggr + (size_t)NN * 64;

  hipMemsetAsync(z1, 0, BSZ * 64 * sizeof(float), stream);
  k_init<<<NN * 64 / 256, 256, 0, stream>>>(x, h);
  for (int layer = 0; layer < 2; ++layer) {
    hipMemsetAsync(aggr, 0, (size_t)NN * 64 * sizeof(float), stream);
    k_gemm64<<<1024, 256, 0, stream>>>(h, Wg + layer * 64 * 64, m);
    k_edge<<<8192, 256, 0, stream>>>(ei, ea, m, aggr);
    // m is dead now; reuse as rbuf
    k_gru_r<<<2048, 64, 0, stream>>>(aggr, h, wih, whh, bih, bhh, m);
    k_gru_zn<<<2048, 64, 0, stream>>>(aggr, h, m, wih, whh, bih, bhh);
  }
  k_mlp1<<<256, 256, 0, stream>>>(h, W1, z1);
  k_tail<<<BSZ / 4, 256, 0, stream>>>(z1, b1, W2, b2, W3, b3, W4, b4, out);
}

// Round 3
// 813.236 us; speedup vs baseline: 2.2443x; 1.4443x over previous
//
#include <hip/hip_runtime.h>
#include <cstdint>

#define BSZ 512
#define NG 5
#define NEL 32
#define IN_C 5
#define HC 64
#define NN (BSZ * NG * NEL)   // 81920 nodes
#define NE (NN * 16)          // 1310720 edges
#define NC 3
#define KTOT (NG * NEL * HC)  // 10240

__device__ __forceinline__ float bcast(float v, int l) {
  return __int_as_float(__builtin_amdgcn_readlane(__float_as_int(v), l));
}

__device__ __forceinline__ float sigmoidf_(float x) {
  return 1.0f / (1.0f + __expf(-x));
}

__device__ __forceinline__ float tanhf_(float x) {
  x = fminf(fmaxf(x, -15.0f), 15.0f);
  float e = __expf(2.0f * x);
  return (e - 1.0f) / (e + 1.0f);
}

// h[n][c] = c < 5 ? x[n][c] : 0
__global__ void k_init(const float* __restrict__ x, float* __restrict__ h) {
  int idx = blockIdx.x * 256 + threadIdx.x;
  int n = idx >> 6, c = idx & 63;
  h[idx] = (c < IN_C) ? x[n * IN_C + c] : 0.0f;
}

// ---------------- CSR build ----------------
__global__ void k_zero_i(int* __restrict__ p) {
  p[blockIdx.x * 256 + threadIdx.x] = 0;
}

__global__ void k_hist(const int* __restrict__ ei, int* __restrict__ cnt) {
  int e = blockIdx.x * 256 + threadIdx.x;
  atomicAdd(&cnt[ei[NE + e]], 1);
}

// per-block exclusive scan of 256 counters; block total to bsum
__global__ void k_scan1(const int* __restrict__ cnt, int* __restrict__ off,
                        int* __restrict__ bsum) {
  __shared__ int s[256];
  int t = threadIdx.x;
  int i = blockIdx.x * 256 + t;
  int v = cnt[i];
  s[t] = v;
  __syncthreads();
  for (int d = 1; d < 256; d <<= 1) {
    int x = (t >= d) ? s[t - d] : 0;
    __syncthreads();
    s[t] += x;
    __syncthreads();
  }
  off[i] = s[t] - v;  // exclusive
  if (t == 255) bsum[blockIdx.x] = s[255];
}

// exclusive scan of 320 block sums (single block)
__global__ void k_scan2(int* __restrict__ bsum) {
  __shared__ int s[320];
  int t = threadIdx.x;
  if (t < 320) s[t] = bsum[t];
  __syncthreads();
  if (t == 0) {
    int run = 0;
    for (int i = 0; i < 320; ++i) { int x = s[i]; s[i] = run; run += x; }
  }
  __syncthreads();
  if (t < 320) bsum[t] = s[t];
}

__global__ void k_scan3(int* __restrict__ off, const int* __restrict__ bsum) {
  int i = blockIdx.x * 256 + threadIdx.x;
  off[i] += bsum[blockIdx.x];
}

// scatter edges into CSR slots; off[n] mutates into row-end pointer
__global__ void k_scatter(const int* __restrict__ ei, const float* __restrict__ ea,
                          int* __restrict__ off, int2* __restrict__ csr) {
  int e = blockIdx.x * 256 + threadIdx.x;
  int dst = ei[NE + e];
  int slot = atomicAdd(&off[dst], 1);
  csr[slot] = make_int2(ei[e], __float_as_int(ea[e]));
}

// ---------------- per-layer kernels ----------------

// m = h @ Wg   ([N,64] @ [64,64]); wave-per-node, Wg column in regs
__global__ void k_gemm64(const float* __restrict__ h, const float* __restrict__ Wg,
                         float* __restrict__ m) {
  const int lane = threadIdx.x & 63;
  const int gw = (blockIdx.x * blockDim.x + threadIdx.x) >> 6;
  const int nw = (gridDim.x * blockDim.x) >> 6;
  float wcol[64];
#pragma unroll
  for (int k = 0; k < 64; ++k) wcol[k] = Wg[k * 64 + lane];
  for (int n = gw; n < NN; n += nw) {
    float hv = h[n * 64 + lane];
    float acc = 0.0f;
#pragma unroll
    for (int k = 0; k < 64; ++k) acc = fmaf(bcast(hv, k), wcol[k], acc);
    m[n * 64 + lane] = acc;
  }
}

// aggr[n] = sum over CSR row n of m[src] * w; wave-per-node, register acc
__global__ void k_aggregate(const int* __restrict__ off, const int* __restrict__ cnt,
                            const int2* __restrict__ csr, const float* __restrict__ m,
                            float* __restrict__ aggr) {
  const int lane = threadIdx.x & 63;
  int wv = (blockIdx.x * blockDim.x + threadIdx.x) >> 6;
  const int nw = (gridDim.x * blockDim.x) >> 6;
  for (int n = wv; n < NN; n += nw) {
    const int r1 = __builtin_amdgcn_readfirstlane(off[n]);   // post-scatter = row end
    const int c = __builtin_amdgcn_readfirstlane(cnt[n]);
    const int r0 = r1 - c;
    float acc = 0.0f;
    for (int i = r0; i < r1; ++i) {
      int2 e = csr[i];
      acc = fmaf(m[(size_t)e.x * 64 + lane], __int_as_float(e.y), acc);
    }
    aggr[n * 64 + lane] = acc;
  }
}

// fused GRU: wave-per-node, all 6 weight columns (384 floats) in unified VGPR/AGPR
// file at 1 wave/SIMD; prefetch next node's rows ahead of the FMA chain.
__global__ void __launch_bounds__(64, 1) k_gru(
    const float* __restrict__ aggr, float* __restrict__ h,
    const float* __restrict__ wih, const float* __restrict__ whh,
    const float* __restrict__ bih, const float* __restrict__ bhh) {
  const int lane = threadIdx.x;
  float wr[64], wz[64], wn[64], vr[64], vz[64], vn[64];
#pragma unroll
  for (int k = 0; k < 64; ++k) {
    wr[k] = wih[lane * 64 + k];
    wz[k] = wih[(64 + lane) * 64 + k];
    wn[k] = wih[(128 + lane) * 64 + k];
    vr[k] = whh[lane * 64 + k];
    vz[k] = whh[(64 + lane) * 64 + k];
    vn[k] = whh[(128 + lane) * 64 + k];
  }
  const float br = bih[lane] + bhh[lane];
  const float bz = bih[64 + lane] + bhh[64 + lane];
  const float bni = bih[128 + lane];
  const float bnh = bhh[128 + lane];
  const int n0 = blockIdx.x;
  float a_cur = (n0 < NN) ? aggr[n0 * 64 + lane] : 0.0f;
  float h_cur = (n0 < NN) ? h[n0 * 64 + lane] : 0.0f;
  for (int n = n0; n < NN; n += gridDim.x) {
    const int nn2 = n + gridDim.x;
    float a_nxt = 0.0f, h_nxt = 0.0f;
    if (nn2 < NN) {
      a_nxt = aggr[nn2 * 64 + lane];
      h_nxt = h[nn2 * 64 + lane];
    }
    float ar = br, az = bz, ani = bni, anh = bnh;
#pragma unroll
    for (int k = 0; k < 64; ++k) {
      float av = bcast(a_cur, k);
      float hb = bcast(h_cur, k);
      ar = fmaf(av, wr[k], ar);
      az = fmaf(av, wz[k], az);
      ani = fmaf(av, wn[k], ani);
      ar = fmaf(hb, vr[k], ar);
      az = fmaf(hb, vz[k], az);
      anh = fmaf(hb, vn[k], anh);
    }
    float r = sigmoidf_(ar);
    float z = sigmoidf_(az);
    float nv = tanhf_(ani + r * anh);
    h[n * 64 + lane] = (1.0f - z) * nv + z * h_cur;
    a_cur = a_nxt;
    h_cur = h_nxt;
  }
}

// z1pre[bs][c] += sum over a K slice of rearranged(h) @ W1.T
__global__ void k_mlp1(const float* __restrict__ h, const float* __restrict__ W1,
                       float* __restrict__ z1) {
  __shared__ float Alds[8 * 512];
  const int tid = threadIdx.x;
  const int grp = blockIdx.x >> 2;   // 0..63
  const int sl = blockIdx.x & 3;     // K slice
  const int bs0 = grp * 8;
  const int c = tid & 63;
  const int w = tid >> 6;            // 0..3
  float acc0 = 0.0f, acc1 = 0.0f;
  for (int ch = 0; ch < 5; ++ch) {
    __syncthreads();
    const int kbase = sl * 2560 + ch * 512;
    for (int idx = tid; idx < 8 * 512; idx += 256) {
      int j = idx >> 9, kk = idx & 511;
      int kg = kbase + kk;
      int e = kg / 320;
      int r = kg - e * 320;
      int g = r >> 6, f = r & 63;
      int n = (bs0 + j) * (NG * NEL) + g * NEL + e;
      Alds[idx] = h[(size_t)n * 64 + f];
    }
    __syncthreads();
    const float* w1p = W1 + (size_t)c * KTOT + kbase;
#pragma unroll 8
    for (int kk = 0; kk < 512; ++kk) {
      float wv = w1p[kk];
      acc0 = fmaf(Alds[w * 512 + kk], wv, acc0);
      acc1 = fmaf(Alds[(w + 4) * 512 + kk], wv, acc1);
    }
  }
  unsafeAtomicAdd(&z1[(bs0 + w) * 64 + c], acc0);
  unsafeAtomicAdd(&z1[(bs0 + w + 4) * 64 + c], acc1);
}

// relu(z1+b1) -> 32 -> 16 -> 3 -> softmax; wave-per-batch-row
__global__ void k_tail(const float* __restrict__ z1, const float* __restrict__ b1,
                       const float* __restrict__ W2, const float* __restrict__ b2,
                       const float* __restrict__ W3, const float* __restrict__ b3,
                       const float* __restrict__ W4, const float* __restrict__ b4,
                       float* __restrict__ out) {
  const int lane = threadIdx.x & 63;
  const int bs = blockIdx.x * 4 + (threadIdx.x >> 6);
  float zv = fmaxf(z1[(size_t)bs * 64 + lane] + b1[lane], 0.0f);
  const int c2 = lane & 31;
  float acc2 = b2[c2];
#pragma unroll
  for (int k = 0; k < 64; ++k) acc2 = fmaf(bcast(zv, k), W2[c2 * 64 + k], acc2);
  acc2 = fmaxf(acc2, 0.0f);
  const int c3 = lane & 15;
  float acc3 = b3[c3];
#pragma unroll
  for (int k = 0; k < 32; ++k) acc3 = fmaf(bcast(acc2, k), W3[c3 * 32 + k], acc3);
  acc3 = fmaxf(acc3, 0.0f);
  float l0 = b4[0], l1 = b4[1], l2 = b4[2];
#pragma unroll
  for (int k = 0; k < 16; ++k) {
    float v = bcast(acc3, k);
    l0 = fmaf(v, W4[k], l0);
    l1 = fmaf(v, W4[16 + k], l1);
    l2 = fmaf(v, W4[32 + k], l2);
  }
  float mx = fmaxf(l0, fmaxf(l1, l2));
  float e0 = __expf(l0 - mx), e1 = __expf(l1 - mx), e2 = __expf(l2 - mx);
  float inv = 1.0f / (e0 + e1 + e2);
  if (lane == 0) {
    out[bs * 3 + 0] = e0 * inv;
    out[bs * 3 + 1] = e1 * inv;
    out[bs * 3 + 2] = e2 * inv;
  }
}

extern "C" void kernel_launch(void* const* d_in, const int* in_sizes, int n_in,
                              void* d_out, int out_size, void* d_ws, size_t ws_size,
                              hipStream_t stream) {
  const float* x = (const float*)d_in[0];
  const int* ei = (const int*)d_in[1];
  const float* ea = (const float*)d_in[2];
  const float* Wg = (const float*)d_in[3];
  const float* wih = (const float*)d_in[4];
  const float* whh = (const float*)d_in[5];
  const float* bih = (const float*)d_in[6];
  const float* bhh = (const float*)d_in[7];
  const float* W1 = (const float*)d_in[8];
  const float* b1 = (const float*)d_in[9];
  const float* W2 = (const float*)d_in[10];
  const float* b2 = (const float*)d_in[11];
  const float* W3 = (const float*)d_in[12];
  const float* b3 = (const float*)d_in[13];
  const float* W4 = (const float*)d_in[14];
  const float* b4 = (const float*)d_in[15];
  float* out = (float*)d_out;

  // workspace layout
  float* h = (float*)d_ws;                         // NN*64
  float* m = h + (size_t)NN * 64;                  // NN*64
  float* aggr = m + (size_t)NN * 64;               // NN*64
  float* z1 = aggr + (size_t)NN * 64;              // BSZ*64
  int* cnt = (int*)(z1 + BSZ * 64);                // NN
  int* off = cnt + NN;                             // NN
  int* bsum = off + NN;                            // 320
  int2* csr = (int2*)(bsum + 512);                 // NE int2

  // --- CSR build (once) ---
  k_zero_i<<<NN / 256, 256, 0, stream>>>(cnt);
  k_hist<<<NE / 256, 256, 0, stream>>>(ei, cnt);
  k_scan1<<<NN / 256, 256, 0, stream>>>(cnt, off, bsum);
  k_scan2<<<1, 512, 0, stream>>>(bsum);
  k_scan3<<<NN / 256, 256, 0, stream>>>(off, bsum);
  k_scatter<<<NE / 256, 256, 0, stream>>>(ei, ea, off, csr);  // off -> row ends

  hipMemsetAsync(z1, 0, BSZ * 64 * sizeof(float), stream);
  k_init<<<NN * 64 / 256, 256, 0, stream>>>(x, h);
  for (int layer = 0; layer < 2; ++layer) {
    k_gemm64<<<1024, 256, 0, stream>>>(h, Wg + layer * 64 * 64, m);
    k_aggregate<<<2048, 256, 0, stream>>>(off, cnt, csr, m, aggr);
    k_gru<<<1024, 64, 0, stream>>>(aggr, h, wih, whh, bih, bhh);
  }
  k_mlp1<<<256, 256, 0, stream>>>(h, W1, z1);
  k_tail<<<BSZ / 4, 256, 0, stream>>>(z1, b1, W2, b2, W3, b3, W4, b4, out);
}